// Round 1
// baseline (1389.410 us; speedup 1.0000x reference)
//
#include <hip/hip_runtime.h>
#include <hip/hip_bf16.h>

#define QQ   1024
#define KLEN 1024
#define BB   4
#define NH   16
#define DD   64
#define RLEN 2048
#define QT   64
#define KT   64
#define LSTR 68   // LDS row stride in floats: 272 B, 16B-aligned, spreads banks

template<bool BF16>
__device__ __forceinline__ float ldf(const void* p, int idx) {
  if constexpr (BF16) {
    return __bfloat162float(reinterpret_cast<const __hip_bfloat16*>(p)[idx]);
  } else {
    return reinterpret_cast<const float*>(p)[idx];
  }
}

__device__ __forceinline__ bool segsel(int mode, const void* p, int idx) {
  if (mode == 0) return reinterpret_cast<const int*>(p)[idx] != 0;
  if (mode == 1) return reinterpret_cast<const float*>(p)[idx] != 0.0f;
  return reinterpret_cast<const unsigned char*>(p)[idx] != 0;
}

// Classifies device buffer dtypes at runtime (deterministic, graph-safe).
// flags[0]: 0 = float inputs are f32, 1 = bf16
// flags[1]: seg_mat is 0 = int32, 1 = f32, 2 = byte/bool
__global__ void detect_kernel(const void* __restrict__ qptr,
                              const void* __restrict__ segptr,
                              int* __restrict__ flags) {
  __shared__ int vb, n01, nf;
  const int tid = threadIdx.x;
  if (tid == 0) { vb = 0; n01 = 0; nf = 0; }
  __syncthreads();
  const unsigned* qw = reinterpret_cast<const unsigned*>(qptr);
  int v = 0;
  for (int i = tid; i < 4096; i += 256) {
    unsigned e = (qw[i] >> 7) & 0xFFu;      // bf16 exponent field of low element
    if (e >= 0x76u && e <= 0x81u) v++;      // N(0,1) magnitudes land here
  }
  const unsigned* sw = reinterpret_cast<const unsigned*>(segptr);
  int a = 0, c = 0;
  for (int i = tid; i < 1024; i += 256) {
    unsigned w = sw[i];
    if (w > 1u) a++;
    if (w != 0u && w != 0x3F800000u) c++;
  }
  atomicAdd(&vb, v);
  atomicAdd(&n01, a);
  atomicAdd(&nf, c);
  __syncthreads();
  if (tid == 0) {
    flags[0] = (vb > 2048) ? 1 : 0;
    flags[1] = (n01 == 0) ? 0 : ((nf == 0) ? 1 : 2);
  }
}

template<bool BF16>
__global__ __launch_bounds__(256) void
attn_kernel(const void* __restrict__ q_head, const void* __restrict__ k_head_h,
            const void* __restrict__ v_head_h, const void* __restrict__ k_head_r,
            const void* __restrict__ seg_embed, const void* __restrict__ r_w_bias,
            const void* __restrict__ r_r_bias, const void* __restrict__ r_s_bias,
            const void* __restrict__ attn_mask, const void* __restrict__ seg_mat,
            void* __restrict__ out, const int* __restrict__ flags) {
  if ((flags[0] != 0) != BF16) return;   // wrong dtype instantiation: no-op
  const int segmode = flags[1];

  extern __shared__ __attribute__((aligned(16))) float smem[];
  float* qa   = smem;                    // [QT][LSTR]  q + r_w_bias
  float* qb   = qa   + QT  * LSTR;       // [QT][LSTR]  q + r_r_bias
  float* kts  = qb   + QT  * LSTR;       // [KT][LSTR]
  float* vts  = kts  + KT  * LSTR;       // [KT][LSTR]
  float* krt  = vts  + KT  * LSTR;       // [128][LSTR] k_r band
  float* Ss   = krt  + 128 * LSTR;       // [QT][LSTR]  scores -> probs
  float* eq0  = Ss   + QT  * LSTR;       // [QT]
  float* eq1  = eq0  + QT;               // [QT]
  float* mrow = eq1  + QT;               // [QT] running max
  float* lrow = mrow + QT;               // [QT] running sum
  float* rsc  = lrow + QT;               // [QT] rescale factor
  float* sv0  = rsc  + QT;               // [DD] seg_embed[0][n]
  float* sv1  = sv0  + DD;               // [DD] seg_embed[1][n]
  float* bdl  = sv1  + DD;               // [DD] r_s_bias - r_w_bias

  const int tid = threadIdx.x;
  const int i0  = blockIdx.x * QT;
  const int bn  = blockIdx.y;
  const int b   = bn >> 4;
  const int n   = bn & 15;

  if (tid < DD) {
    const int d = tid;
    sv0[d] = ldf<BF16>(seg_embed, (0 * NH + n) * DD + d);
    sv1[d] = ldf<BF16>(seg_embed, (1 * NH + n) * DD + d);
    bdl[d] = ldf<BF16>(r_s_bias, n * DD + d) - ldf<BF16>(r_w_bias, n * DD + d);
  }
  for (int e = tid; e < QT * DD; e += 256) {
    const int il = e >> 6, d = e & 63;
    const float qv = ldf<BF16>(q_head, (((i0 + il) * BB + b) * NH + n) * DD + d);
    qa[il * LSTR + d] = qv + ldf<BF16>(r_w_bias, n * DD + d);
    qb[il * LSTR + d] = qv + ldf<BF16>(r_r_bias, n * DD + d);
  }
  __syncthreads();
  if (tid < QT) {
    float a0 = 0.f, a1 = 0.f;
    for (int d = 0; d < DD; d++) {
      const float qc = qa[tid * LSTR + d] + bdl[d];   // = q + r_s_bias
      a0 = fmaf(qc, sv0[d], a0);
      a1 = fmaf(qc, sv1[d], a1);
    }
    eq0[tid] = a0; eq1[tid] = a1;
    mrow[tid] = -1e30f; lrow[tid] = 0.f;
  }

  const int ig    = tid >> 4;        // 0..15 -> owns query rows irow..irow+3
  const int sg    = tid & 15;        // j-group (scores) / d-group (PV)
  const int irow  = ig * 4;
  const int jcol  = sg * 4;
  const int diagb = jcol - irow + (QT - 1);   // k_r band row for (ii=0,jj=0)

  float accO[4][4];
#pragma unroll
  for (int ii = 0; ii < 4; ii++)
#pragma unroll
    for (int dd2 = 0; dd2 < 4; dd2++) accO[ii][dd2] = 0.f;

  for (int t = 0; t < KLEN / KT; t++) {
    const int j0 = t * KT;
    const int rbase = QQ + j0 - i0 - (QT - 1);   // >= 1 always
    __syncthreads();   // prior PV done before restaging
    for (int e = tid; e < KT * DD; e += 256) {
      const int jl = e >> 6, d = e & 63;
      const int gidx = (((j0 + jl) * BB + b) * NH + n) * DD + d;
      kts[jl * LSTR + d] = ldf<BF16>(k_head_h, gidx);
      vts[jl * LSTR + d] = ldf<BF16>(v_head_h, gidx);
    }
    for (int e = tid; e < 128 * DD; e += 256) {
      const int rr = e >> 6, d = e & 63;
      int r = rbase + rr;
      if (r > RLEN - 1) r = RLEN - 1;   // slot 127 can overshoot; unused
      krt[rr * LSTR + d] = ldf<BF16>(k_head_r, ((r * BB + b) * NH + n) * DD + d);
    }
    __syncthreads();

    // ---- scores: acc[ii][jj] = dot(qa,k) + dot(qb,kr[j-i+Q]) ----
    float acc[4][4];
#pragma unroll
    for (int ii = 0; ii < 4; ii++)
#pragma unroll
      for (int jj = 0; jj < 4; jj++) acc[ii][jj] = 0.f;

    for (int dc = 0; dc < DD / 4; dc++) {
      const int dof = dc * 4;
      float4 a4[4], b4[4], k4[4], r4[7];
#pragma unroll
      for (int ii = 0; ii < 4; ii++) {
        a4[ii] = *reinterpret_cast<const float4*>(&qa[(irow + ii) * LSTR + dof]);
        b4[ii] = *reinterpret_cast<const float4*>(&qb[(irow + ii) * LSTR + dof]);
      }
#pragma unroll
      for (int jj = 0; jj < 4; jj++)
        k4[jj] = *reinterpret_cast<const float4*>(&kts[(jcol + jj) * LSTR + dof]);
#pragma unroll
      for (int x = 0; x < 7; x++)
        r4[x] = *reinterpret_cast<const float4*>(&krt[(diagb - 3 + x) * LSTR + dof]);
#pragma unroll
      for (int ii = 0; ii < 4; ii++) {
#pragma unroll
        for (int jj = 0; jj < 4; jj++) {
          const float4 kk = k4[jj];
          const float4 rr4 = r4[jj - ii + 3];
          const float4 aa = a4[ii];
          const float4 bb = b4[ii];
          float s = acc[ii][jj];
          s = fmaf(aa.x, kk.x, s);  s = fmaf(aa.y, kk.y, s);
          s = fmaf(aa.z, kk.z, s);  s = fmaf(aa.w, kk.w, s);
          s = fmaf(bb.x, rr4.x, s); s = fmaf(bb.y, rr4.y, s);
          s = fmaf(bb.z, rr4.z, s); s = fmaf(bb.w, rr4.w, s);
          acc[ii][jj] = s;
        }
      }
    }

    // ---- finalize scores (seg term, scale, mask) -> LDS ----
#pragma unroll
    for (int ii = 0; ii < 4; ii++) {
      const int gi = i0 + irow + ii;
      const float e0 = eq0[irow + ii], e1 = eq1[irow + ii];
      float sr[4];
#pragma unroll
      for (int jj = 0; jj < 4; jj++) {
        const int gj = j0 + jcol + jj;
        const int sidx = (gi * KLEN + gj) * BB + b;
        const float ef = segsel(segmode, seg_mat, sidx) ? e1 : e0;
        const float msk = ldf<BF16>(attn_mask, sidx);
        sr[jj] = (acc[ii][jj] + ef) * 0.125f - 1e30f * msk;
      }
      float4 srow; srow.x = sr[0]; srow.y = sr[1]; srow.z = sr[2]; srow.w = sr[3];
      *reinterpret_cast<float4*>(&Ss[(irow + ii) * LSTR + jcol]) = srow;
    }
    __syncthreads();

    // ---- online softmax (one thread per row) ----
    if (tid < QT) {
      const float mo = mrow[tid];
      float mx = mo;
      for (int j = 0; j < KT; j++) mx = fmaxf(mx, Ss[tid * LSTR + j]);
      const float f = __expf(mo - mx);
      float sum = 0.f;
      for (int j = 0; j < KT; j++) {
        const float p = __expf(Ss[tid * LSTR + j] - mx);
        Ss[tid * LSTR + j] = p;
        sum += p;
      }
      mrow[tid] = mx;
      lrow[tid] = lrow[tid] * f + sum;
      rsc[tid]  = f;
    }
    __syncthreads();

    // ---- PV accumulate: thread owns rows irow..+3, cols d = jcol..+3 ----
#pragma unroll
    for (int ii = 0; ii < 4; ii++) {
      const float f = rsc[irow + ii];
#pragma unroll
      for (int dd2 = 0; dd2 < 4; dd2++) accO[ii][dd2] *= f;
    }
    for (int j4 = 0; j4 < KT / 4; j4++) {
      float4 p4[4], v4[4];
#pragma unroll
      for (int ii = 0; ii < 4; ii++)
        p4[ii] = *reinterpret_cast<const float4*>(&Ss[(irow + ii) * LSTR + j4 * 4]);
#pragma unroll
      for (int jj = 0; jj < 4; jj++)
        v4[jj] = *reinterpret_cast<const float4*>(&vts[(j4 * 4 + jj) * LSTR + jcol]);
#pragma unroll
      for (int ii = 0; ii < 4; ii++) {
        const float pv[4] = {p4[ii].x, p4[ii].y, p4[ii].z, p4[ii].w};
#pragma unroll
        for (int jj = 0; jj < 4; jj++) {
          accO[ii][0] = fmaf(pv[jj], v4[jj].x, accO[ii][0]);
          accO[ii][1] = fmaf(pv[jj], v4[jj].y, accO[ii][1]);
          accO[ii][2] = fmaf(pv[jj], v4[jj].z, accO[ii][2]);
          accO[ii][3] = fmaf(pv[jj], v4[jj].w, accO[ii][3]);
        }
      }
    }
  }

  // ---- epilogue: out[i,b,n,d] = accO / l ----
#pragma unroll
  for (int ii = 0; ii < 4; ii++) {
    const float linv = 1.0f / lrow[irow + ii];
    const int gi = i0 + irow + ii;
    const int oidx = ((gi * BB + b) * NH + n) * DD + jcol;
    if constexpr (BF16) {
      __hip_bfloat16* op = reinterpret_cast<__hip_bfloat16*>(out);
      op[oidx + 0] = __float2bfloat16(accO[ii][0] * linv);
      op[oidx + 1] = __float2bfloat16(accO[ii][1] * linv);
      op[oidx + 2] = __float2bfloat16(accO[ii][2] * linv);
      op[oidx + 3] = __float2bfloat16(accO[ii][3] * linv);
    } else {
      float4 o;
      o.x = accO[ii][0] * linv; o.y = accO[ii][1] * linv;
      o.z = accO[ii][2] * linv; o.w = accO[ii][3] * linv;
      *reinterpret_cast<float4*>(reinterpret_cast<float*>(out) + oidx) = o;
    }
  }
}

extern "C" void kernel_launch(void* const* d_in, const int* in_sizes, int n_in,
                              void* d_out, int out_size, void* d_ws, size_t ws_size,
                              hipStream_t stream) {
  int* flags = reinterpret_cast<int*>(d_ws);
  hipLaunchKernelGGL(detect_kernel, dim3(1), dim3(256), 0, stream,
                     (const void*)d_in[0], (const void*)d_in[9], flags);
  dim3 grid(QQ / QT, BB * NH);
  const size_t lds = 30976u * sizeof(float);  // 123,904 B dynamic LDS
  hipLaunchKernelGGL((attn_kernel<false>), grid, dim3(256), lds, stream,
                     (const void*)d_in[0], (const void*)d_in[1], (const void*)d_in[2],
                     (const void*)d_in[3], (const void*)d_in[4], (const void*)d_in[5],
                     (const void*)d_in[6], (const void*)d_in[7], (const void*)d_in[8],
                     (const void*)d_in[9], d_out, flags);
  hipLaunchKernelGGL((attn_kernel<true>), grid, dim3(256), lds, stream,
                     (const void*)d_in[0], (const void*)d_in[1], (const void*)d_in[2],
                     (const void*)d_in[3], (const void*)d_in[4], (const void*)d_in[5],
                     (const void*)d_in[6], (const void*)d_in[7], (const void*)d_in[8],
                     (const void*)d_in[9], d_out, flags);
}

// Round 3
// 373.566 us; speedup vs baseline: 3.7193x; 3.7193x over previous
//
#include <hip/hip_runtime.h>

typedef __attribute__((ext_vector_type(8))) short short8;
typedef __attribute__((ext_vector_type(4))) float f32x4;
typedef __attribute__((ext_vector_type(4))) unsigned int u32x4;

#define K_OFF   0
#define KR_OFF  8192
#define V_OFF   24576
#define P_OFF   32768
#define BD_OFF  40960
#define EQ_OFF  62464
#define SMEM_SZ 62976

union S8U { u32x4 u; short8 s; };

__device__ __forceinline__ unsigned short f2bf(float x) {
  unsigned u = __float_as_uint(x);
  return (unsigned short)((u + 0x7FFFu + ((u >> 16) & 1u)) >> 16);
}
__device__ __forceinline__ unsigned pk2(float a, float b) {
  return (unsigned)f2bf(a) | ((unsigned)f2bf(b) << 16);
}
struct HL { unsigned h, l; };
__device__ __forceinline__ HL split2(float a, float b) {
  unsigned short ha = f2bf(a), hb = f2bf(b);
  float ra = a - __uint_as_float(((unsigned)ha) << 16);
  float rb = b - __uint_as_float(((unsigned)hb) << 16);
  HL o;
  o.h = (unsigned)ha | ((unsigned)hb << 16);
  o.l = (unsigned)f2bf(ra) | ((unsigned)f2bf(rb) << 16);
  return o;
}

// seg_mat dtype probe: flags[0] = 0:int32  1:f32  2:byte/bool
__global__ void detect_kernel(const unsigned* __restrict__ segw, int* __restrict__ flags) {
  if (threadIdx.x >= 64) return;
  int a = 0, c = 0;
  for (int i = threadIdx.x; i < 1024; i += 64) {
    unsigned v = segw[i];
    if (v > 1u) a++;
    if (v != 0u && v != 0x3F800000u) c++;
  }
  for (int m = 1; m < 64; m <<= 1) { a += __shfl_xor(a, m); c += __shfl_xor(c, m); }
  if (threadIdx.x == 0) flags[0] = (a == 0) ? 0 : ((c == 0) ? 1 : 2);
}

#define MFMA16(A, B, C) __builtin_amdgcn_mfma_f32_16x16x32_bf16((A), (B), (C), 0, 0, 0)

__global__ __launch_bounds__(256, 2) void
attn_mfma(const float* __restrict__ q_head, const float* __restrict__ k_head_h,
          const float* __restrict__ v_head_h, const float* __restrict__ k_head_r,
          const float* __restrict__ seg_embed, const float* __restrict__ r_w_bias,
          const float* __restrict__ r_r_bias, const float* __restrict__ r_s_bias,
          const float* __restrict__ attn_mask, const void* __restrict__ seg_mat,
          float* __restrict__ out, const int* __restrict__ flags) {
  __shared__ __attribute__((aligned(128))) unsigned char smem[SMEM_SZ];
  const int segmode = flags[0];
  const int tid = threadIdx.x;
  const int w = tid >> 6, l = tid & 63;
  const int g = l >> 4, lan16 = l & 15;
  const int i0 = blockIdx.x * 64;
  const int bn = blockIdx.y, b = bn >> 4, n = bn & 15;

  // ---------- per-lane Q fragments (hi/lo split) + seg-dot partials ----------
  const int qrow = i0 + 16 * w + lan16;
  const float* qp = q_head + (size_t)qrow * 4096 + b * 1024 + n * 64;
  S8U qa_h[2], qa_l[2], qb_h[2], qb_l[2];
  float e0p = 0.f, e1p = 0.f;
#pragma unroll
  for (int kc = 0; kc < 2; kc++) {
    const int d0 = kc * 32 + g * 8;
    float4 qv0 = *(const float4*)(qp + d0);
    float4 qv1 = *(const float4*)(qp + d0 + 4);
    float4 wb0 = *(const float4*)(r_w_bias + n * 64 + d0);
    float4 wb1 = *(const float4*)(r_w_bias + n * 64 + d0 + 4);
    float4 rb0 = *(const float4*)(r_r_bias + n * 64 + d0);
    float4 rb1 = *(const float4*)(r_r_bias + n * 64 + d0 + 4);
    float4 sb0 = *(const float4*)(r_s_bias + n * 64 + d0);
    float4 sb1 = *(const float4*)(r_s_bias + n * 64 + d0 + 4);
    float4 s00 = *(const float4*)(seg_embed + n * 64 + d0);
    float4 s01 = *(const float4*)(seg_embed + n * 64 + d0 + 4);
    float4 s10 = *(const float4*)(seg_embed + 1024 + n * 64 + d0);
    float4 s11 = *(const float4*)(seg_embed + 1024 + n * 64 + d0 + 4);
    unsigned ah[4], al[4], bh[4], bl[4];
    {
      HL t;
      t = split2(qv0.x + wb0.x, qv0.y + wb0.y); ah[0] = t.h; al[0] = t.l;
      t = split2(qv0.z + wb0.z, qv0.w + wb0.w); ah[1] = t.h; al[1] = t.l;
      t = split2(qv1.x + wb1.x, qv1.y + wb1.y); ah[2] = t.h; al[2] = t.l;
      t = split2(qv1.z + wb1.z, qv1.w + wb1.w); ah[3] = t.h; al[3] = t.l;
      t = split2(qv0.x + rb0.x, qv0.y + rb0.y); bh[0] = t.h; bl[0] = t.l;
      t = split2(qv0.z + rb0.z, qv0.w + rb0.w); bh[1] = t.h; bl[1] = t.l;
      t = split2(qv1.x + rb1.x, qv1.y + rb1.y); bh[2] = t.h; bl[2] = t.l;
      t = split2(qv1.z + rb1.z, qv1.w + rb1.w); bh[3] = t.h; bl[3] = t.l;
    }
    qa_h[kc].u = (u32x4){ah[0], ah[1], ah[2], ah[3]};
    qa_l[kc].u = (u32x4){al[0], al[1], al[2], al[3]};
    qb_h[kc].u = (u32x4){bh[0], bh[1], bh[2], bh[3]};
    qb_l[kc].u = (u32x4){bl[0], bl[1], bl[2], bl[3]};
    float c0;
    c0 = qv0.x + sb0.x; e0p = fmaf(c0, s00.x, e0p); e1p = fmaf(c0, s10.x, e1p);
    c0 = qv0.y + sb0.y; e0p = fmaf(c0, s00.y, e0p); e1p = fmaf(c0, s10.y, e1p);
    c0 = qv0.z + sb0.z; e0p = fmaf(c0, s00.z, e0p); e1p = fmaf(c0, s10.z, e1p);
    c0 = qv0.w + sb0.w; e0p = fmaf(c0, s00.w, e0p); e1p = fmaf(c0, s10.w, e1p);
    c0 = qv1.x + sb1.x; e0p = fmaf(c0, s01.x, e0p); e1p = fmaf(c0, s11.x, e1p);
    c0 = qv1.y + sb1.y; e0p = fmaf(c0, s01.y, e0p); e1p = fmaf(c0, s11.y, e1p);
    c0 = qv1.z + sb1.z; e0p = fmaf(c0, s01.z, e0p); e1p = fmaf(c0, s11.z, e1p);
    c0 = qv1.w + sb1.w; e0p = fmaf(c0, s01.w, e0p); e1p = fmaf(c0, s11.w, e1p);
  }
  e0p += __shfl_xor(e0p, 16); e0p += __shfl_xor(e0p, 32);
  e1p += __shfl_xor(e1p, 16); e1p += __shfl_xor(e1p, 32);
  float* eq0 = (float*)(smem + EQ_OFF);
  float* eq1 = eq0 + 64;
  if (g == 0) { eq0[16 * w + lan16] = e0p; eq1[16 * w + lan16] = e1p; }
  float eqa0[4], eqa1[4];
#pragma unroll
  for (int r = 0; r < 4; r++) {
    eqa0[r] = eq0[16 * w + 4 * g + r];
    eqa1[r] = eq1[16 * w + 4 * g + r];
  }

  const unsigned swK = (unsigned)((lan16 & 7) << 4);

  float m_[4], l_[4];
  f32x4 accO[4];
#pragma unroll
  for (int r = 0; r < 4; r++) { m_[r] = -1e30f; l_[r] = 0.f; }
#pragma unroll
  for (int dt = 0; dt < 4; dt++) accO[dt] = (f32x4){0.f, 0.f, 0.f, 0.f};

  for (int t = 0; t < 16; t++) {
    const int j0 = t * 64;
    __syncthreads();
    // ---- stage K (row-major [j][d], swizzled) ----
    {
      const int jj = tid >> 2, dblk = tid & 3;
      const unsigned swJ = (unsigned)((jj & 7) << 4);
      const float* kp = k_head_h + (size_t)(j0 + jj) * 4096 + b * 1024 + n * 64 + dblk * 16;
      float4 a0 = *(const float4*)(kp);
      float4 a1 = *(const float4*)(kp + 4);
      float4 a2 = *(const float4*)(kp + 8);
      float4 a3 = *(const float4*)(kp + 12);
      u32x4 w0 = (u32x4){pk2(a0.x, a0.y), pk2(a0.z, a0.w), pk2(a1.x, a1.y), pk2(a1.z, a1.w)};
      u32x4 w1 = (u32x4){pk2(a2.x, a2.y), pk2(a2.z, a2.w), pk2(a3.x, a3.y), pk2(a3.z, a3.w)};
      *(u32x4*)(smem + K_OFF + jj * 128 + ((unsigned)(dblk * 32) ^ swJ)) = w0;
      *(u32x4*)(smem + K_OFF + jj * 128 + ((unsigned)(dblk * 32 + 16) ^ swJ)) = w1;
    }
    // ---- stage V TRANSPOSED: Vt[d][j] (row-major, swizzled) ----
    {
      const int d2 = tid & 31;       // d-pair: covers d = 2*d2, 2*d2+1
      const int jc = tid >> 5;       // j-chunk of 8
      const float* vp = v_head_h + (size_t)(j0 + jc * 8) * 4096 + b * 1024 + n * 64 + 2 * d2;
      float2 e[8];
#pragma unroll
      for (int q8 = 0; q8 < 8; q8++)
        e[q8] = *(const float2*)(vp + (size_t)q8 * 4096);
      u32x4 wA = (u32x4){pk2(e[0].x, e[1].x), pk2(e[2].x, e[3].x),
                         pk2(e[4].x, e[5].x), pk2(e[6].x, e[7].x)};
      u32x4 wB = (u32x4){pk2(e[0].y, e[1].y), pk2(e[2].y, e[3].y),
                         pk2(e[4].y, e[5].y), pk2(e[6].y, e[7].y)};
      const int dA = 2 * d2, dB = 2 * d2 + 1;
      *(u32x4*)(smem + V_OFF + dA * 128 +
                ((unsigned)(jc * 16) ^ ((unsigned)(dA & 7) << 4))) = wA;
      *(u32x4*)(smem + V_OFF + dB * 128 +
                ((unsigned)(jc * 16) ^ ((unsigned)(dB & 7) << 4))) = wB;
    }
    // ---- stage k_r band (128 rows, swizzled) ----
    {
      const int rr = tid >> 1, dh = tid & 1;
      const unsigned swR = (unsigned)((rr & 7) << 4);
      const int rbase = 1024 + j0 - i0 - 63;
      int r = rbase + rr; if (r > 2047) r = 2047;
      const float* rp = k_head_r + (size_t)r * 4096 + b * 1024 + n * 64 + dh * 32;
#pragma unroll
      for (int h = 0; h < 4; h++) {
        float4 a0 = *(const float4*)(rp + h * 8);
        float4 a1 = *(const float4*)(rp + h * 8 + 4);
        u32x4 ww = (u32x4){pk2(a0.x, a0.y), pk2(a0.z, a0.w), pk2(a1.x, a1.y), pk2(a1.z, a1.w)};
        *(u32x4*)(smem + KR_OFF + rr * 128 + ((unsigned)(dh * 64 + h * 16) ^ swR)) = ww;
      }
    }
    __syncthreads();

    // ---- mask + seg prefetch (overlaps with MFMA below) ----
    float mskv[4][4], efv[4][4];
#pragma unroll
    for (int c = 0; c < 4; c++) {
#pragma unroll
      for (int r = 0; r < 4; r++) {
        const int sidx = ((i0 + 16 * w + 4 * g + r) * 1024 + (j0 + 16 * c + lan16)) * 4 + b;
        mskv[c][r] = attn_mask[sidx];
        bool sv;
        if (segmode == 0)      sv = ((const int*)seg_mat)[sidx] != 0;
        else if (segmode == 1) sv = ((const float*)seg_mat)[sidx] != 0.0f;
        else                   sv = ((const unsigned char*)seg_mat)[sidx] != 0;
        efv[c][r] = sv ? eqa1[r] : eqa0[r];
      }
    }

    __builtin_amdgcn_s_setprio(1);
    // ---- ac = (q + r_w_bias) K^T ----
    f32x4 acc[4];
#pragma unroll
    for (int c = 0; c < 4; c++) {
      acc[c] = (f32x4){0.f, 0.f, 0.f, 0.f};
#pragma unroll
      for (int kc = 0; kc < 2; kc++) {
        S8U bf;
        bf.u = *(const u32x4*)(smem + K_OFF + (16 * c + lan16) * 128 +
                               ((unsigned)(kc * 64 + g * 16) ^ swK));
        acc[c] = MFMA16(qa_h[kc].s, bf.s, acc[c]);
        acc[c] = MFMA16(qa_l[kc].s, bf.s, acc[c]);
      }
    }
    // ---- bd band = (q + r_r_bias) Kr_band^T -> per-wave LDS rows ----
    float* bdp = (float*)(smem + BD_OFF);
#pragma unroll
    for (int tr = 0; tr < 5; tr++) {
      f32x4 bda = (f32x4){0.f, 0.f, 0.f, 0.f};
      const int rowb = 48 - 16 * w + 16 * tr + lan16;
#pragma unroll
      for (int kc = 0; kc < 2; kc++) {
        S8U bf;
        bf.u = *(const u32x4*)(smem + KR_OFF + rowb * 128 +
                               ((unsigned)(kc * 64 + g * 16) ^ swK));
        bda = MFMA16(qb_h[kc].s, bf.s, bda);
        bda = MFMA16(qb_l[kc].s, bf.s, bda);
      }
#pragma unroll
      for (int r = 0; r < 4; r++)
        bdp[(16 * w + 4 * g + r) * 84 + 16 * tr + lan16] = bda[r];
    }
    __builtin_amdgcn_s_setprio(0);

    // ---- finalize scores + online softmax ----
    float p[4][4];
#pragma unroll
    for (int r = 0; r < 4; r++) {
      const int qloc = 4 * g + r;
      float sc[4];
#pragma unroll
      for (int c = 0; c < 4; c++) {
        const int jl = 16 * c + lan16;
        const float bd = bdp[(16 * w + qloc) * 84 + (jl - qloc + 15)];
        sc[c] = (acc[c][r] + bd + efv[c][r]) * 0.125f - 1e30f * mskv[c][r];
      }
      float mx = fmaxf(fmaxf(sc[0], sc[1]), fmaxf(sc[2], sc[3]));
      mx = fmaxf(mx, __shfl_xor(mx, 1));
      mx = fmaxf(mx, __shfl_xor(mx, 2));
      mx = fmaxf(mx, __shfl_xor(mx, 4));
      mx = fmaxf(mx, __shfl_xor(mx, 8));
      const float mn = fmaxf(m_[r], mx);
      const float f = __expf(m_[r] - mn);
      float sum = 0.f;
#pragma unroll
      for (int c = 0; c < 4; c++) { p[c][r] = __expf(sc[c] - mn); sum += p[c][r]; }
      sum += __shfl_xor(sum, 1);
      sum += __shfl_xor(sum, 2);
      sum += __shfl_xor(sum, 4);
      sum += __shfl_xor(sum, 8);
      l_[r] = l_[r] * f + sum;
      m_[r] = mn;
#pragma unroll
      for (int dt = 0; dt < 4; dt++) accO[dt][r] *= f;
    }
    // ---- write P (bf16, row-major [q][j], swizzled) ----
#pragma unroll
    for (int c = 0; c < 4; c++) {
#pragma unroll
      for (int r = 0; r < 4; r++) {
        const int row = 16 * w + 4 * g + r;
        const unsigned col2 = (unsigned)((16 * c + lan16) * 2);
        *(unsigned short*)(smem + P_OFF + row * 128 +
                           (col2 ^ (((unsigned)((4 * g + r) & 7)) << 4))) = f2bf(p[c][r]);
      }
    }
    // ---- PV: P A-frags + Vt B-frags (plain swizzled LDS reads) ----
    S8U pa[2];
#pragma unroll
    for (int kc = 0; kc < 2; kc++)
      pa[kc].u = *(const u32x4*)(smem + P_OFF + (16 * w + lan16) * 128 +
                                 ((unsigned)(kc * 64 + g * 16) ^ swK));
    __builtin_amdgcn_s_setprio(1);
#pragma unroll
    for (int dt = 0; dt < 4; dt++) {
      const int drow = 16 * dt + lan16;
      S8U v0, v1;
      v0.u = *(const u32x4*)(smem + V_OFF + drow * 128 + ((unsigned)(g * 16) ^ swK));
      v1.u = *(const u32x4*)(smem + V_OFF + drow * 128 + ((unsigned)(64 + g * 16) ^ swK));
      accO[dt] = MFMA16(pa[0].s, v0.s, accO[dt]);
      accO[dt] = MFMA16(pa[1].s, v1.s, accO[dt]);
    }
    __builtin_amdgcn_s_setprio(0);
  }

  // ---- epilogue ----
#pragma unroll
  for (int r = 0; r < 4; r++) {
    const float linv = 1.0f / l_[r];
    const int q = i0 + 16 * w + 4 * g + r;
    float* op = out + (size_t)q * 4096 + b * 1024 + n * 64 + lan16;
#pragma unroll
    for (int dt = 0; dt < 4; dt++) op[dt * 16] = accO[dt][r] * linv;
  }
}

extern "C" void kernel_launch(void* const* d_in, const int* in_sizes, int n_in,
                              void* d_out, int out_size, void* d_ws, size_t ws_size,
                              hipStream_t stream) {
  int* flags = reinterpret_cast<int*>(d_ws);
  hipLaunchKernelGGL(detect_kernel, dim3(1), dim3(64), 0, stream,
                     (const unsigned*)d_in[9], flags);
  dim3 grid(16, 64);
  hipLaunchKernelGGL(attn_mfma, grid, dim3(256), 0, stream,
                     (const float*)d_in[0], (const float*)d_in[1], (const float*)d_in[2],
                     (const float*)d_in[3], (const float*)d_in[4], (const float*)d_in[5],
                     (const float*)d_in[6], (const float*)d_in[7], (const float*)d_in[8],
                     (const void*)d_in[9], (float*)d_out, flags);
}